// Round 5
// baseline (337.884 us; speedup 1.0000x reference)
//
#include <hip/hip_runtime.h>
#include <hip/hip_bf16.h>
#include <math.h>

// Problem constants
#define NN 96
#define SS 4096
#define PP 4096
#define PH 1024
#define PHH 512
#define TP 3267            // TOTAL_PARAMS
#define KC_SPLIT 16
#define KCHUNK 256         // 4096 / 16
#define NG 6               // n-groups in gemm
#define NACC 16            // accumulators per thread in gemm

typedef short short8 __attribute__((ext_vector_type(8)));   // MFMA A/B frag (8 bf16)
typedef float float4v __attribute__((ext_vector_type(4)));  // MFMA C/D frag

__device__ __forceinline__ float stp(float x) {
    float sp = (x > 15.0f) ? x : log1pf(expf(x));
    return sp * (1.0f / 6.0f);
}

__device__ __forceinline__ float sin_w0(float x) {
    // sin(30*x) via Cody-Waite reduction to revolutions + v_sin_f32
    constexpr double Cd = 30.0 / 6.283185307179586476925286766559;
    constexpr float C_hi = (float)Cd;
    constexpr float C_lo = (float)(Cd - (double)C_hi);
    float t = x * C_hi;
    float k = rintf(t);
    float r = fmaf(x, C_hi, -k);
    r = fmaf(x, C_lo, r);
    return __builtin_amdgcn_sinf(r);
}

// bf16 round-to-nearest-even helpers (bit ops; values finite)
__device__ __forceinline__ unsigned short f2bf(float f) {
    unsigned u = __float_as_uint(f);
    unsigned r = u + 0x7fffu + ((u >> 16) & 1u);
    return (unsigned short)(r >> 16);
}
__device__ __forceinline__ float bf2f(unsigned short b) {
    return __uint_as_float(((unsigned)b) << 16);
}
// split v into hi+lo bf16, pack into u32 (hi in upper half)
__device__ __forceinline__ unsigned splitpack(float v) {
    unsigned short hb = f2bf(v);
    unsigned short lb = f2bf(v - bf2f(hb));
    return (((unsigned)hb) << 16) | (unsigned)lb;
}

// ---------------- Kernel 1: build zT[p][n] ----------------
__global__ __launch_bounds__(256) void z_kernel(
    const float* __restrict__ loc, const float* __restrict__ log_scale,
    const float* __restrict__ h_loc, const float* __restrict__ h_ls,
    const float* __restrict__ hh_loc, const float* __restrict__ hh_ls,
    const float* __restrict__ eps, const float* __restrict__ h_eps,
    const float* __restrict__ hh_eps,
    const int* __restrict__ h_gi, const int* __restrict__ hh_gi,
    float* __restrict__ zT)
{
    int t = blockIdx.x * 256 + threadIdx.x;
    int n = t % NN;
    int p = t / NN;
    int idx = n * PP + p;
    float s = loc[idx] + eps[idx] * stp(log_scale[idx]);
    int g  = h_gi[p];
    int gh = (n >> 4) * PH + g;
    float hs = h_loc[gh] + h_eps[gh] * stp(h_ls[gh]);
    int gg = hh_gi[p];
    float hhs = hh_loc[gg] + hh_eps[gg] * stp(hh_ls[gg]);
    zT[p * NN + n] = s + hs + hhs;
}

// ---------------- Kernel 2: fp32 GEMM partials (unchanged this round) ----------------
__global__ __launch_bounds__(256, 6) void gemm_kernel(
    const float* __restrict__ Wm, const float* __restrict__ zT,
    float* __restrict__ partials)
{
    int b = blockIdx.x;
    int jtkc = b % 208;
    int ng   = b / 208;
    int kc = jtkc % KC_SPLIT;
    int jt = jtkc / KC_SPLIT;
    int j = jt * 256 + threadIdx.x;
    if (j >= TP) return;
    int n0 = ng * NACC;

    float acc[NACC];
#pragma unroll
    for (int i = 0; i < NACC; ++i) acc[i] = 0.0f;

    const float* wp = Wm + (size_t)(kc * KCHUNK) * TP + j;
    const float* zp = zT + (size_t)(kc * KCHUNK) * NN + n0;

    float wcur[8], wnext[8];
#pragma unroll
    for (int u = 0; u < 8; ++u) wcur[u] = wp[(size_t)u * TP];

#pragma unroll 1
    for (int p = 0; p < KCHUNK / 8 - 1; ++p) {
        const float* wpn = wp + (size_t)(p + 1) * 8 * TP;
#pragma unroll
        for (int u = 0; u < 8; ++u) wnext[u] = wpn[(size_t)u * TP];
        const float* zr = zp + (size_t)p * 8 * NN;
#pragma unroll
        for (int u = 0; u < 8; ++u) {
            float w = wcur[u];
#pragma unroll
            for (int i = 0; i < NACC; ++i)
                acc[i] = fmaf(zr[u * NN + i], w, acc[i]);
        }
#pragma unroll
        for (int u = 0; u < 8; ++u) wcur[u] = wnext[u];
    }
    {
        const float* zr = zp + (size_t)(KCHUNK - 8) * NN;
#pragma unroll
        for (int u = 0; u < 8; ++u) {
            float w = wcur[u];
#pragma unroll
            for (int i = 0; i < NACC; ++i)
                acc[i] = fmaf(zr[u * NN + i], w, acc[i]);
        }
    }

    float* pp = partials + ((size_t)(kc * NN + n0)) * TP + j;
#pragma unroll
    for (int i = 0; i < NACC; ++i) { *pp = acc[i]; pp += TP; }
}

// ---------------- Kernel 3: reduce partials + bias ----------------
__global__ __launch_bounds__(256) void reduce_kernel(
    const float* __restrict__ partials, const float* __restrict__ b_map,
    float* __restrict__ params)
{
    int t = blockIdx.x * 256 + threadIdx.x;
    if (t >= NN * TP) return;
    int j = t % TP;
    int n = t / TP;
    float a = b_map[j];
#pragma unroll
    for (int kc = 0; kc < KC_SPLIT; ++kc)
        a += partials[((size_t)(kc * NN + n)) * TP + j];
    params[(size_t)n * TP + j] = a;
}

// ---------------- Kernel 4: SIREN MLP via split-bf16 MFMA ----------------
// 1536 blocks (96 n x 16 chunks) x 256 threads (4 waves). Each wave: 4 iters
// of a 16-point tile. Weights preloaded once per block into VGPR B-frags as
// bf16 hi/lo pairs; per layer: acc = bias; acc += Ahi*Bhi + Alo*Bhi + Ahi*Blo.
// C->A transpose between layers via per-wave LDS tile (stride-18 rows, 2-way
// banks = free), wave-local so only lgkmcnt+sched_barrier, no __syncthreads.
#define TSTRIDE 18
__global__ __launch_bounds__(256, 4) void mlp_kernel(
    const float* __restrict__ x, const float* __restrict__ params,
    float* __restrict__ out)
{
    int b = blockIdx.x;
    int n = b >> 4;
    int chunk = b & 15;
    int tid = threadIdx.x;
    int wave = tid >> 6;
    int lane = tid & 63;
    int e  = lane & 15;          // role: B col / C col / A row / tile point-col
    int q4 = (lane >> 4) << 2;   // 4-block: A k-offset, C row-block, tile col-block

    __shared__ unsigned tiles[4][32 * TSTRIDE];
    unsigned* tp = tiles[wave];

    const float* pr = params + (size_t)n * TP;

    // ---- preload B-frags (bf16 hi/lo) + biases, once per block ----
    short8 Bhi[4][2], Blo[4][2];
    float bias0[4], bias1[3];
#pragma unroll
    for (int L = 0; L < 3; ++L) {
        const float* lp = pr + L * 1056;
        bias0[L] = lp[e];
        bias1[L] = lp[e + 16];
#pragma unroll
        for (int h = 0; h < 2; ++h) {
#pragma unroll
            for (int i = 0; i < 8; ++i) {
                int k = ((i >> 2) << 4) + q4 + (i & 3);
                float w = lp[32 + k * 32 + e + h * 16];
                unsigned short hb = f2bf(w);
                Bhi[L][h][i] = (short)hb;
                Blo[L][h][i] = (short)f2bf(w - bf2f(hb));
            }
        }
    }
    {   // final layer 32 -> 3 (cols >= 3 zero)
        const float* lpf = pr + 3168;
        bias0[3] = (e < 3) ? lpf[e] : 0.0f;
#pragma unroll
        for (int i = 0; i < 8; ++i) {
            int k = ((i >> 2) << 4) + q4 + (i & 3);
            float w = (e < 3) ? lpf[3 + k * 3 + e] : 0.0f;
            unsigned short hb = f2bf(w);
            Bhi[3][0][i] = (short)hb;
            Blo[3][0][i] = (short)f2bf(w - bf2f(hb));
        }
    }

    int p0 = chunk * 256 + wave * 64;

#pragma unroll 1
    for (int it = 0; it < 4; ++it) {
        int m0 = p0 + it * 16;

        // ---- layer 0: A directly from x (row = m0+e, k-chunks at q4, q4+16) ----
        short8 Ahi, Alo;
        {
            const float* xr = x + ((size_t)(n * SS + m0 + e)) * 32;
            float4 xa = *(const float4*)(xr + q4);
            float4 xb = *(const float4*)(xr + 16 + q4);
            float xv[8] = {xa.x, xa.y, xa.z, xa.w, xb.x, xb.y, xb.z, xb.w};
#pragma unroll
            for (int i = 0; i < 8; ++i) {
                unsigned short hb = f2bf(xv[i]);
                Ahi[i] = (short)hb;
                Alo[i] = (short)f2bf(xv[i] - bf2f(hb));
            }
        }

        float4v acc0, acc1;
#pragma unroll 1
        for (int L = 0; L < 3; ++L) {
            acc0 = (float4v){bias0[L], bias0[L], bias0[L], bias0[L]};
            acc1 = (float4v){bias1[L], bias1[L], bias1[L], bias1[L]};
            acc0 = __builtin_amdgcn_mfma_f32_16x16x32_bf16(Ahi, Bhi[L][0], acc0, 0, 0, 0);
            acc0 = __builtin_amdgcn_mfma_f32_16x16x32_bf16(Alo, Bhi[L][0], acc0, 0, 0, 0);
            acc0 = __builtin_amdgcn_mfma_f32_16x16x32_bf16(Ahi, Blo[L][0], acc0, 0, 0, 0);
            acc1 = __builtin_amdgcn_mfma_f32_16x16x32_bf16(Ahi, Bhi[L][1], acc1, 0, 0, 0);
            acc1 = __builtin_amdgcn_mfma_f32_16x16x32_bf16(Alo, Bhi[L][1], acc1, 0, 0, 0);
            acc1 = __builtin_amdgcn_mfma_f32_16x16x32_bf16(Ahi, Blo[L][1], acc1, 0, 0, 0);

            // ---- sin + split + transpose via wave-local LDS tile ----
            // lane holds C cols e,e+16 for points q4..q4+3 -> write tile[e][pt]
            unsigned pk[8];
#pragma unroll
            for (int r = 0; r < 4; ++r) {
                pk[r]     = splitpack(sin_w0(acc0[r]));
                pk[4 + r] = splitpack(sin_w0(acc1[r]));
            }
            *(uint2*)(tp + e * TSTRIDE + q4)            = make_uint2(pk[0], pk[1]);
            *(uint2*)(tp + e * TSTRIDE + q4 + 2)        = make_uint2(pk[2], pk[3]);
            *(uint2*)(tp + (e + 16) * TSTRIDE + q4)     = make_uint2(pk[4], pk[5]);
            *(uint2*)(tp + (e + 16) * TSTRIDE + q4 + 2) = make_uint2(pk[6], pk[7]);
            asm volatile("s_waitcnt lgkmcnt(0)" ::: "memory");
            __builtin_amdgcn_sched_barrier(0);
            // read A-frag: row(point)=e, k = (i>>2)*16 + q4 + (i&3)
#pragma unroll
            for (int i = 0; i < 8; ++i) {
                int k = ((i >> 2) << 4) + q4 + (i & 3);
                unsigned u = tp[k * TSTRIDE + e];
                Ahi[i] = (short)(u >> 16);
                Alo[i] = (short)(u & 0xffffu);
            }
        }

        // ---- final layer 32 -> 3 ----
        float4v accF = (float4v){bias0[3], bias0[3], bias0[3], bias0[3]};
        accF = __builtin_amdgcn_mfma_f32_16x16x32_bf16(Ahi, Bhi[3][0], accF, 0, 0, 0);
        accF = __builtin_amdgcn_mfma_f32_16x16x32_bf16(Alo, Bhi[3][0], accF, 0, 0, 0);
        accF = __builtin_amdgcn_mfma_f32_16x16x32_bf16(Ahi, Blo[3][0], accF, 0, 0, 0);

        if (e < 3) {
#pragma unroll
            for (int r = 0; r < 4; ++r)
                out[((size_t)n * SS + m0 + q4 + r) * 3 + e] = accF[r];
        }
    }
}

extern "C" void kernel_launch(void* const* d_in, const int* in_sizes, int n_in,
                              void* d_out, int out_size, void* d_ws, size_t ws_size,
                              hipStream_t stream)
{
    const float* x        = (const float*)d_in[0];
    const float* loc      = (const float*)d_in[1];
    const float* log_sc   = (const float*)d_in[2];
    const float* h_loc    = (const float*)d_in[3];
    const float* h_ls     = (const float*)d_in[4];
    const float* hh_loc   = (const float*)d_in[5];
    const float* hh_ls    = (const float*)d_in[6];
    const float* eps      = (const float*)d_in[7];
    const float* h_eps    = (const float*)d_in[8];
    const float* hh_eps   = (const float*)d_in[9];
    const float* W_map    = (const float*)d_in[10];
    const float* b_map    = (const float*)d_in[11];
    const int*   h_gi     = (const int*)d_in[12];
    const int*   hh_gi    = (const int*)d_in[13];
    float* out = (float*)d_out;

    float* zT       = (float*)d_ws;
    float* partials = zT + (size_t)PP * NN;
    float* params   = partials + (size_t)KC_SPLIT * NN * TP;

    z_kernel<<<(NN * PP) / 256, 256, 0, stream>>>(
        loc, log_sc, h_loc, h_ls, hh_loc, hh_ls, eps, h_eps, hh_eps,
        h_gi, hh_gi, zT);

    gemm_kernel<<<NG * 208, 256, 0, stream>>>(W_map, zT, partials);

    reduce_kernel<<<(NN * TP + 255) / 256, 256, 0, stream>>>(partials, b_map, params);

    mlp_kernel<<<96 * 16, 256, 0, stream>>>(x, params, out);
}

// Round 6
// 86.750 us; speedup vs baseline: 3.8949x; 3.8949x over previous
//
#include <hip/hip_runtime.h>
#include <hip/hip_bf16.h>
#include <math.h>

// Problem constants
#define NN 96
#define SS 4096
#define PP 4096
#define PH 1024
#define PHH 512
#define TP 3267            // TOTAL_PARAMS
#define KC_SPLIT 16
#define KCHUNK 256         // 4096 / 16
#define NG 6               // n-groups in gemm
#define NACC 16            // accumulators per thread in gemm

typedef short short8 __attribute__((ext_vector_type(8)));   // MFMA A/B frag (8 bf16)
typedef float float4v __attribute__((ext_vector_type(4)));  // MFMA C/D frag

__device__ __forceinline__ float stp(float x) {
    float sp = (x > 15.0f) ? x : log1pf(expf(x));
    return sp * (1.0f / 6.0f);
}

__device__ __forceinline__ float sin_w0(float x) {
    // sin(30*x) via Cody-Waite reduction to revolutions + v_sin_f32
    constexpr double Cd = 30.0 / 6.283185307179586476925286766559;
    constexpr float C_hi = (float)Cd;
    constexpr float C_lo = (float)(Cd - (double)C_hi);
    float t = x * C_hi;
    float k = rintf(t);
    float r = fmaf(x, C_hi, -k);
    r = fmaf(x, C_lo, r);
    return __builtin_amdgcn_sinf(r);
}

// bf16 round-to-nearest-even helpers (bit ops; values finite)
__device__ __forceinline__ unsigned short f2bf(float f) {
    unsigned u = __float_as_uint(f);
    unsigned r = u + 0x7fffu + ((u >> 16) & 1u);
    return (unsigned short)(r >> 16);
}
__device__ __forceinline__ float bf2f(unsigned short b) {
    return __uint_as_float(((unsigned)b) << 16);
}
// split v into hi+lo bf16, pack into u32 (hi in upper half)
__device__ __forceinline__ unsigned splitpack(float v) {
    unsigned short hb = f2bf(v);
    unsigned short lb = f2bf(v - bf2f(hb));
    return (((unsigned)hb) << 16) | (unsigned)lb;
}

// ---------------- Kernel 1: build zT[p][n] ----------------
__global__ __launch_bounds__(256) void z_kernel(
    const float* __restrict__ loc, const float* __restrict__ log_scale,
    const float* __restrict__ h_loc, const float* __restrict__ h_ls,
    const float* __restrict__ hh_loc, const float* __restrict__ hh_ls,
    const float* __restrict__ eps, const float* __restrict__ h_eps,
    const float* __restrict__ hh_eps,
    const int* __restrict__ h_gi, const int* __restrict__ hh_gi,
    float* __restrict__ zT)
{
    int t = blockIdx.x * 256 + threadIdx.x;
    int n = t % NN;
    int p = t / NN;
    int idx = n * PP + p;
    float s = loc[idx] + eps[idx] * stp(log_scale[idx]);
    int g  = h_gi[p];
    int gh = (n >> 4) * PH + g;
    float hs = h_loc[gh] + h_eps[gh] * stp(h_ls[gh]);
    int gg = hh_gi[p];
    float hhs = hh_loc[gg] + hh_eps[gg] * stp(hh_ls[gg]);
    zT[p * NN + n] = s + hs + hhs;
}

// ---------------- Kernel 2: fp32 GEMM partials (unchanged) ----------------
__global__ __launch_bounds__(256, 6) void gemm_kernel(
    const float* __restrict__ Wm, const float* __restrict__ zT,
    float* __restrict__ partials)
{
    int b = blockIdx.x;
    int jtkc = b % 208;
    int ng   = b / 208;
    int kc = jtkc % KC_SPLIT;
    int jt = jtkc / KC_SPLIT;
    int j = jt * 256 + threadIdx.x;
    if (j >= TP) return;
    int n0 = ng * NACC;

    float acc[NACC];
#pragma unroll
    for (int i = 0; i < NACC; ++i) acc[i] = 0.0f;

    const float* wp = Wm + (size_t)(kc * KCHUNK) * TP + j;
    const float* zp = zT + (size_t)(kc * KCHUNK) * NN + n0;

    float wcur[8], wnext[8];
#pragma unroll
    for (int u = 0; u < 8; ++u) wcur[u] = wp[(size_t)u * TP];

#pragma unroll 1
    for (int p = 0; p < KCHUNK / 8 - 1; ++p) {
        const float* wpn = wp + (size_t)(p + 1) * 8 * TP;
#pragma unroll
        for (int u = 0; u < 8; ++u) wnext[u] = wpn[(size_t)u * TP];
        const float* zr = zp + (size_t)p * 8 * NN;
#pragma unroll
        for (int u = 0; u < 8; ++u) {
            float w = wcur[u];
#pragma unroll
            for (int i = 0; i < NACC; ++i)
                acc[i] = fmaf(zr[u * NN + i], w, acc[i]);
        }
#pragma unroll
        for (int u = 0; u < 8; ++u) wcur[u] = wnext[u];
    }
    {
        const float* zr = zp + (size_t)(KCHUNK - 8) * NN;
#pragma unroll
        for (int u = 0; u < 8; ++u) {
            float w = wcur[u];
#pragma unroll
            for (int i = 0; i < NACC; ++i)
                acc[i] = fmaf(zr[u * NN + i], w, acc[i]);
        }
    }

    float* pp = partials + ((size_t)(kc * NN + n0)) * TP + j;
#pragma unroll
    for (int i = 0; i < NACC; ++i) { *pp = acc[i]; pp += TP; }
}

// ---------------- Kernel 3: reduce partials + bias ----------------
__global__ __launch_bounds__(256) void reduce_kernel(
    const float* __restrict__ partials, const float* __restrict__ b_map,
    float* __restrict__ params)
{
    int t = blockIdx.x * 256 + threadIdx.x;
    if (t >= NN * TP) return;
    int j = t % TP;
    int n = t / TP;
    float a = b_map[j];
#pragma unroll
    for (int kc = 0; kc < KC_SPLIT; ++kc)
        a += partials[((size_t)(kc * NN + n)) * TP + j];
    params[(size_t)n * TP + j] = a;
}

// ---------------- Kernel 4: SIREN MLP via split-bf16 MFMA ----------------
// All B-fragments are NAMED registers (statically indexed everywhere) --
// rule #20: runtime-indexed ext_vector arrays go to scratch. Layer pipeline
// fully unrolled via macros.
#define TSTRIDE 18

// preload one 32x16 weight half-column into hi/lo bf16 frags
#define PRELOAD_HALF(lp, off, BH, BL)                                   \
    {                                                                   \
        _Pragma("unroll")                                               \
        for (int i = 0; i < 8; ++i) {                                   \
            int k = ((i >> 2) << 4) + q4 + (i & 3);                     \
            float w = (lp)[32 + k * 32 + e + (off)];                    \
            unsigned short hb = f2bf(w);                                \
            BH[i] = (short)hb;                                          \
            BL[i] = (short)f2bf(w - bf2f(hb));                          \
        }                                                               \
    }

// one hidden layer: 6 MFMAs + sin/split + LDS transpose back into Ahi/Alo
#define LAYER(BH0, BL0, BH1, BL1, B0, B1)                               \
    {                                                                   \
        float4v acc0 = (float4v){B0, B0, B0, B0};                       \
        float4v acc1 = (float4v){B1, B1, B1, B1};                       \
        acc0 = __builtin_amdgcn_mfma_f32_16x16x32_bf16(Ahi, BH0, acc0, 0, 0, 0); \
        acc0 = __builtin_amdgcn_mfma_f32_16x16x32_bf16(Alo, BH0, acc0, 0, 0, 0); \
        acc0 = __builtin_amdgcn_mfma_f32_16x16x32_bf16(Ahi, BL0, acc0, 0, 0, 0); \
        acc1 = __builtin_amdgcn_mfma_f32_16x16x32_bf16(Ahi, BH1, acc1, 0, 0, 0); \
        acc1 = __builtin_amdgcn_mfma_f32_16x16x32_bf16(Alo, BH1, acc1, 0, 0, 0); \
        acc1 = __builtin_amdgcn_mfma_f32_16x16x32_bf16(Ahi, BL1, acc1, 0, 0, 0); \
        unsigned pk0 = splitpack(sin_w0(acc0[0]));                      \
        unsigned pk1 = splitpack(sin_w0(acc0[1]));                      \
        unsigned pk2 = splitpack(sin_w0(acc0[2]));                      \
        unsigned pk3 = splitpack(sin_w0(acc0[3]));                      \
        unsigned pk4 = splitpack(sin_w0(acc1[0]));                      \
        unsigned pk5 = splitpack(sin_w0(acc1[1]));                      \
        unsigned pk6 = splitpack(sin_w0(acc1[2]));                      \
        unsigned pk7 = splitpack(sin_w0(acc1[3]));                      \
        *(uint2*)(tp + e * TSTRIDE + q4)            = make_uint2(pk0, pk1); \
        *(uint2*)(tp + e * TSTRIDE + q4 + 2)        = make_uint2(pk2, pk3); \
        *(uint2*)(tp + (e + 16) * TSTRIDE + q4)     = make_uint2(pk4, pk5); \
        *(uint2*)(tp + (e + 16) * TSTRIDE + q4 + 2) = make_uint2(pk6, pk7); \
        asm volatile("s_waitcnt lgkmcnt(0)" ::: "memory");              \
        __builtin_amdgcn_sched_barrier(0);                              \
        _Pragma("unroll")                                               \
        for (int i = 0; i < 8; ++i) {                                   \
            int k = ((i >> 2) << 4) + q4 + (i & 3);                     \
            unsigned u = tp[k * TSTRIDE + e];                           \
            Ahi[i] = (short)(u >> 16);                                  \
            Alo[i] = (short)(u & 0xffffu);                              \
        }                                                               \
    }

__global__ __launch_bounds__(256, 3) void mlp_kernel(
    const float* __restrict__ x, const float* __restrict__ params,
    float* __restrict__ out)
{
    int b = blockIdx.x;
    int n = b >> 4;
    int chunk = b & 15;
    int tid = threadIdx.x;
    int wave = tid >> 6;
    int lane = tid & 63;
    int e  = lane & 15;          // role: B col / C col / A row / tile point-col
    int q4 = (lane >> 4) << 2;   // 4-block: A k-offset, C row-block, tile col-block

    __shared__ unsigned tiles[4][32 * TSTRIDE];
    unsigned* tp = tiles[wave];

    const float* pr = params + (size_t)n * TP;

    // ---- preload ALL weights as named VGPR frags, once per block ----
    short8 B0h0, B0l0, B0h1, B0l1;   // layer 0
    short8 B1h0, B1l0, B1h1, B1l1;   // layer 1
    short8 B2h0, B2l0, B2h1, B2l1;   // layer 2
    short8 BFh, BFl;                 // final 32->3
    float b0_0, b0_1, b1_0, b1_1, b2_0, b2_1, bF;

    { const float* lp = pr;            b0_0 = lp[e]; b0_1 = lp[e + 16];
      PRELOAD_HALF(lp, 0, B0h0, B0l0)  PRELOAD_HALF(lp, 16, B0h1, B0l1) }
    { const float* lp = pr + 1056;     b1_0 = lp[e]; b1_1 = lp[e + 16];
      PRELOAD_HALF(lp, 0, B1h0, B1l0)  PRELOAD_HALF(lp, 16, B1h1, B1l1) }
    { const float* lp = pr + 2112;     b2_0 = lp[e]; b2_1 = lp[e + 16];
      PRELOAD_HALF(lp, 0, B2h0, B2l0)  PRELOAD_HALF(lp, 16, B2h1, B2l1) }
    {   // final layer 32 -> 3 (cols >= 3 zero)
        const float* lpf = pr + 3168;
        bF = (e < 3) ? lpf[e] : 0.0f;
#pragma unroll
        for (int i = 0; i < 8; ++i) {
            int k = ((i >> 2) << 4) + q4 + (i & 3);
            float w = (e < 3) ? lpf[3 + k * 3 + e] : 0.0f;
            unsigned short hb = f2bf(w);
            BFh[i] = (short)hb;
            BFl[i] = (short)f2bf(w - bf2f(hb));
        }
    }

    int p0 = chunk * 256 + wave * 64;

#pragma unroll 1
    for (int it = 0; it < 4; ++it) {
        int m0 = p0 + it * 16;

        // ---- layer-0 input: A directly from x ----
        short8 Ahi, Alo;
        {
            const float* xr = x + ((size_t)(n * SS + m0 + e)) * 32;
            float4 xa = *(const float4*)(xr + q4);
            float4 xb = *(const float4*)(xr + 16 + q4);
            float xv[8] = {xa.x, xa.y, xa.z, xa.w, xb.x, xb.y, xb.z, xb.w};
#pragma unroll
            for (int i = 0; i < 8; ++i) {
                unsigned short hb = f2bf(xv[i]);
                Ahi[i] = (short)hb;
                Alo[i] = (short)f2bf(xv[i] - bf2f(hb));
            }
        }

        LAYER(B0h0, B0l0, B0h1, B0l1, b0_0, b0_1)
        LAYER(B1h0, B1l0, B1h1, B1l1, b1_0, b1_1)
        LAYER(B2h0, B2l0, B2h1, B2l1, b2_0, b2_1)

        // ---- final layer 32 -> 3 ----
        float4v accF = (float4v){bF, bF, bF, bF};
        accF = __builtin_amdgcn_mfma_f32_16x16x32_bf16(Ahi, BFh, accF, 0, 0, 0);
        accF = __builtin_amdgcn_mfma_f32_16x16x32_bf16(Alo, BFh, accF, 0, 0, 0);
        accF = __builtin_amdgcn_mfma_f32_16x16x32_bf16(Ahi, BFl, accF, 0, 0, 0);

        if (e < 3) {
#pragma unroll
            for (int r = 0; r < 4; ++r)
                out[((size_t)n * SS + m0 + q4 + r) * 3 + e] = accF[r];
        }
    }
}

extern "C" void kernel_launch(void* const* d_in, const int* in_sizes, int n_in,
                              void* d_out, int out_size, void* d_ws, size_t ws_size,
                              hipStream_t stream)
{
    const float* x        = (const float*)d_in[0];
    const float* loc      = (const float*)d_in[1];
    const float* log_sc   = (const float*)d_in[2];
    const float* h_loc    = (const float*)d_in[3];
    const float* h_ls     = (const float*)d_in[4];
    const float* hh_loc   = (const float*)d_in[5];
    const float* hh_ls    = (const float*)d_in[6];
    const float* eps      = (const float*)d_in[7];
    const float* h_eps    = (const float*)d_in[8];
    const float* hh_eps   = (const float*)d_in[9];
    const float* W_map    = (const float*)d_in[10];
    const float* b_map    = (const float*)d_in[11];
    const int*   h_gi     = (const int*)d_in[12];
    const int*   hh_gi    = (const int*)d_in[13];
    float* out = (float*)d_out;

    float* zT       = (float*)d_ws;
    float* partials = zT + (size_t)PP * NN;
    float* params   = partials + (size_t)KC_SPLIT * NN * TP;

    z_kernel<<<(NN * PP) / 256, 256, 0, stream>>>(
        loc, log_sc, h_loc, h_ls, hh_loc, hh_ls, eps, h_eps, hh_eps,
        h_gi, hh_gi, zT);

    gemm_kernel<<<NG * 208, 256, 0, stream>>>(W_map, zT, partials);

    reduce_kernel<<<(NN * TP + 255) / 256, 256, 0, stream>>>(partials, b_map, params);

    mlp_kernel<<<96 * 16, 256, 0, stream>>>(x, params, out);
}